// Round 5
// baseline (345.865 us; speedup 1.0000x reference)
//
#include <hip/hip_runtime.h>

// MotherCubeConv: out[n,:] = concat(features[n,:], prev[idx[n,0..3],:]) @ W^T + b
// Gathered GEMM [200000 x 640] x [640 x 128] via bf16 MFMA, 3-term hi/lo split:
//   A*W ~= A_hi*W_hi + A_lo*W_hi + A_hi*W_lo
// v5: round-4 + A-gather software pipeline. 8 waves x 32 rows (acc=64 AGPR),
// A loads for phase p+1 issued during phase p (ping-pong reg sets aA/aB);
// the __syncthreads vmcnt(0) drain guarantees they've landed -> compute phases
// are stall-free. W fragments staged in LDS (double-buffered, global_load_lds).

#define N_PTS  200000
#define F_INN  128
#define K_TOT  640      // 5 * F_IN
#define NCT    4        // 128 cols / 32

typedef __attribute__((ext_vector_type(8)))  short bf16x8;   // MFMA A/B operand
typedef __attribute__((ext_vector_type(16))) float f32x16;   // MFMA C/D (32x32)
typedef __attribute__((ext_vector_type(8)))  float f32x8;

union Frag { bf16x8 v; unsigned int u[4]; };

__device__ __forceinline__ unsigned int bf_rne_bits(float f) {
    unsigned int u = __builtin_bit_cast(unsigned int, f);
    return (u + 0x7FFFu + ((u >> 16) & 1u)) & 0xFFFF0000u;
}

// RNE split — W only (once over 80 KB)
__device__ __forceinline__ void split8_rne(const f32x8 a, bf16x8& hi, bf16x8& lo) {
    Frag H, L;
#pragma unroll
    for (int p = 0; p < 4; ++p) {
        float f0 = a[2 * p], f1 = a[2 * p + 1];
        unsigned int h0 = bf_rne_bits(f0), h1 = bf_rne_bits(f1);
        float r0 = f0 - __builtin_bit_cast(float, h0);
        float r1 = f1 - __builtin_bit_cast(float, h1);
        unsigned int l0 = bf_rne_bits(r0), l1 = bf_rne_bits(r1);
        H.u[p] = (h0 >> 16) | h1;
        L.u[p] = (l0 >> 16) | l1;
    }
    hi = H.v; lo = L.v;
}

// Truncation split — A hot path
__device__ __forceinline__ void split8_trunc(const f32x8 a, bf16x8& hi, bf16x8& lo) {
    Frag H, L;
#pragma unroll
    for (int p = 0; p < 4; ++p) {
        float f0 = a[2 * p], f1 = a[2 * p + 1];
        unsigned int u0 = __builtin_bit_cast(unsigned int, f0);
        unsigned int u1 = __builtin_bit_cast(unsigned int, f1);
        unsigned int h0 = u0 & 0xFFFF0000u, h1 = u1 & 0xFFFF0000u;
        float r0 = f0 - __builtin_bit_cast(float, h0);
        float r1 = f1 - __builtin_bit_cast(float, h1);
        unsigned int l0 = __builtin_bit_cast(unsigned int, r0);
        unsigned int l1 = __builtin_bit_cast(unsigned int, r1);
        H.u[p] = (h0 >> 16) | h1;
        L.u[p] = (l0 >> 16) | (l1 & 0xFFFF0000u);
    }
    hi = H.v; lo = L.v;
}

// Pre-kernel: W [128 x 640] fp32 -> fragment-ready bf16 hi/lo, phase-contiguous:
// byte offset of frag(t, ct, h, lane) = ((t*4+ct)*2 + h)*1024 + lane*16
// k-map (matches A loads): c = ct*32+(lane&31), k = t*16+(lane>>5)*8+j
__global__ void build_wf(const float* __restrict__ W, bf16x8* __restrict__ wfbuf) {
    int tid = blockIdx.x * blockDim.x + threadIdx.x;
    int lane = tid & 63;
    int ct   = (tid >> 6) & 3;
    int t    = tid >> 8;
    if (t >= 40) return;
    int c = ct * 32 + (lane & 31);
    int k = t * 16 + (lane >> 5) * 8;
    f32x8 w = *(const f32x8*)(W + (size_t)c * K_TOT + k);
    bf16x8 h, l;
    split8_rne(w, h, l);
    wfbuf[((t * 4 + ct) * 2 + 0) * 64 + lane] = h;
    wfbuf[((t * 4 + ct) * 2 + 1) * 64 + lane] = l;
}

__global__ __launch_bounds__(512, 2)
void mcconv(const float* __restrict__ feat, const float* __restrict__ prev,
            const int* __restrict__ nbr, const float* __restrict__ bias,
            const char* __restrict__ wfbuf, float* __restrict__ out) {
    __shared__ char smem[2 * 32768];   // double-buffered 32 KB phase

    const int lane = threadIdx.x & 63;
    const int wave = threadIdx.x >> 6;
    const int g    = lane >> 5;
    const int r31  = lane & 31;
    const int n0   = blockIdx.x * 256 + wave * 32;   // wave's 32 rows

    int nA  = n0 + r31;
    int nAc = nA < N_PTS ? nA : N_PTS - 1;
    const int4 iA = *(const int4*)(nbr + 4 * (size_t)nAc);

    const float* s0 = feat + (size_t)nAc  * F_INN;
    const float* s1 = prev + (size_t)iA.x * F_INN;
    const float* s2 = prev + (size_t)iA.y * F_INN;
    const float* s3 = prev + (size_t)iA.z * F_INN;
    const float* s4 = prev + (size_t)iA.w * F_INN;

    f32x16 acc[NCT];
#pragma unroll
    for (int c = 0; c < NCT; ++c)
#pragma unroll
        for (int i = 0; i < 16; ++i) acc[c][i] = 0.0f;

    // stage one 32 KB wf phase: 512 threads x 4 x global_load_lds(16B)
    auto STAGE = [&](int buf, int phase) {
        const char* gsrc = wfbuf + (size_t)phase * 32768 + wave * 4096 + lane * 16;
        char* ldst = smem + buf * 32768 + wave * 4096;
#pragma unroll
        for (int i = 0; i < 4; ++i) {
            __builtin_amdgcn_global_load_lds(
                (const __attribute__((address_space(1))) unsigned int*)(gsrc + i * 1024),
                (__attribute__((address_space(3))) unsigned int*)(ldst + i * 1024),
                16, 0, 0);
        }
    };

    // issue the 4 A-chunk loads of `phase` (segment = phase/2, chunks (phase&1)*4..+3)
    auto PRE = [&](f32x8 (&dst)[4], int phase) {
        const int s = phase >> 1;
        const float* p = (s == 0) ? s0 : (s == 1) ? s1 : (s == 2) ? s2 : (s == 3) ? s3 : s4;
        const int cc0 = (phase & 1) * 4;
#pragma unroll
        for (int c = 0; c < 4; ++c)
            dst[c] = *(const f32x8*)(p + (cc0 + c) * 16 + g * 8);
    };

    auto COMPUTE = [&](int buf, f32x8 (&a)[4]) {
        const char* fb = smem + buf * 32768;
#pragma unroll
        for (int c = 0; c < 4; ++c) {
            bf16x8 ah, al;
            split8_trunc(a[c], ah, al);
#pragma unroll
            for (int ct = 0; ct < NCT; ++ct) {
                bf16x8 bh = *(const bf16x8*)(fb + c * 8192 + ct * 2048 +        lane * 16);
                bf16x8 bl = *(const bf16x8*)(fb + c * 8192 + ct * 2048 + 1024 + lane * 16);
                acc[ct] = __builtin_amdgcn_mfma_f32_32x32x16_bf16(ah, bh, acc[ct], 0, 0, 0);
                acc[ct] = __builtin_amdgcn_mfma_f32_32x32x16_bf16(al, bh, acc[ct], 0, 0, 0);
                acc[ct] = __builtin_amdgcn_mfma_f32_32x32x16_bf16(ah, bl, acc[ct], 0, 0, 0);
            }
        }
    };

    f32x8 aA[4], aB[4];

    PRE(aA, 0);
    STAGE(0, 0);
    __syncthreads();   // vmcnt(0) drain: wf(0) in LDS, aA landed

    // 10 phases, 2 per segment, fully unrolled; ping-pong {buf, A-reg set}
#pragma unroll
    for (int pp = 0; pp < 5; ++pp) {
        const int p0 = 2 * pp, p1 = 2 * pp + 1;
        STAGE(1, p0 + 1);          // wf for next phase -> other buffer
        PRE(aB, p0 + 1);           // A for next phase -> other reg set
        COMPUTE(0, aA);            // stall-free: data landed last barrier
        __syncthreads();
        if (p1 < 9) {
            STAGE(0, p1 + 1);
            PRE(aA, p1 + 1);
        }
        COMPUTE(1, aB);
        __syncthreads();
    }

    // epilogue: bias + store. C/D layout: col = lane&31,
    // row = (reg&3) + 8*(reg>>2) + 4*(lane>>5)
    float bcol[NCT];
#pragma unroll
    for (int ct = 0; ct < NCT; ++ct) bcol[ct] = bias[ct * 32 + r31];

#pragma unroll
    for (int reg = 0; reg < 16; ++reg) {
        const int row = n0 + (reg & 3) + 8 * (reg >> 2) + 4 * g;
        if (row < N_PTS) {
#pragma unroll
            for (int ct = 0; ct < NCT; ++ct)
                out[(size_t)row * F_INN + ct * 32 + r31] = acc[ct][reg] + bcol[ct];
        }
    }
}

extern "C" void kernel_launch(void* const* d_in, const int* in_sizes, int n_in,
                              void* d_out, int out_size, void* d_ws, size_t ws_size,
                              hipStream_t stream) {
    const float* feat = (const float*)d_in[0];
    const float* prev = (const float*)d_in[1];
    const int*   nbr  = (const int*)d_in[2];
    const float* W    = (const float*)d_in[3];
    const float* bias = (const float*)d_in[4];
    float* out = (float*)d_out;

    bf16x8* wfbuf = (bf16x8*)d_ws;   // 320 KiB, phase-contiguous

    hipLaunchKernelGGL(build_wf, dim3(40), dim3(256), 0, stream, W, wfbuf);

    const int grid = (N_PTS + 255) / 256;   // 782 blocks, 8 waves x 32 rows
    hipLaunchKernelGGL(mcconv, dim3(grid), dim3(512), 0, stream,
                       feat, prev, nbr, bias, (const char*)wfbuf, out);
}